// Round 1
// baseline (699.237 us; speedup 1.0000x reference)
//
#include <hip/hip_runtime.h>
#include <hip/hip_bf16.h>

typedef __bf16 bf16_t;
typedef __bf16 bf16x8 __attribute__((ext_vector_type(8)));
typedef float f32x4 __attribute__((ext_vector_type(4)));

static constexpr int S_LEN = 2048;
static constexpr int NBATCH = 2;
static constexpr int DM = 1024;
static constexpr int NH = 16;
static constexpr int HD = 64;
static constexpr int DFF = 4096;
static constexpr int MROWS = NBATCH * S_LEN;   // 4096

// ---------------- RoPE cos/sin table: cs[0..S*64) = cos, cs[S*64..) = sin ---------
__global__ __launch_bounds__(256) void rope_table_k(float* __restrict__ cs) {
  int idx = blockIdx.x * 256 + threadIdx.x;     // 0 .. 2048*32-1
  int i = idx & 31, s = idx >> 5;
  float inv = powf(10000.0f, -(float)i / 32.0f);  // theta^{-2i/64}
  float ang = (float)s * inv;
  float c = cosf(ang), sn = sinf(ang);
  cs[s * 64 + i] = c;  cs[s * 64 + i + 32] = c;
  cs[S_LEN * 64 + s * 64 + i] = sn;  cs[S_LEN * 64 + s * 64 + i + 32] = sn;
}

// ---------------- time-emb MLP: h = silu(te @ w1 + b1) -----------------------------
__global__ __launch_bounds__(256) void time_mlp1_k(const float* __restrict__ te,
    const float* __restrict__ w1, const float* __restrict__ b1, float* __restrict__ h) {
  int idx = blockIdx.x * 256 + threadIdx.x;     // 0..B*1024-1
  int b = idx >> 10, j = idx & 1023;
  const float* t = te + b * DM;
  float acc = b1[j];
  for (int i = 0; i < DM; ++i) acc += t[i] * w1[(size_t)i * DM + j];
  h[idx] = acc / (1.0f + expf(-acc));
}

// ---------------- ss = h @ w2 + b2  ([B][2048]: scale | shift) ---------------------
__global__ __launch_bounds__(256) void time_mlp2_k(const float* __restrict__ h,
    const float* __restrict__ w2, const float* __restrict__ b2, float* __restrict__ ss) {
  int idx = blockIdx.x * 256 + threadIdx.x;     // 0..B*2048-1
  int b = idx >> 11, j = idx & 2047;
  const float* hb = h + b * DM;
  float acc = b2[j];
  for (int i = 0; i < DM; ++i) acc += hb[i] * w2[(size_t)i * 2048 + j];
  ss[idx] = acc;
}

// ---------------- ada-RMSNorm: out = x*rsqrt(mean x^2+eps)*w*(1+scale)+shift -------
__global__ __launch_bounds__(256) void ada_rms_k(const float* __restrict__ x,
    const float* __restrict__ wnorm, const float* __restrict__ ss,
    bf16_t* __restrict__ out) {
  int row = blockIdx.x;                // 0..4095  (b = row/2048)
  int b = row >> 11;
  const float* xr = x + (size_t)row * DM;
  float xl[4]; float s = 0.f;
#pragma unroll
  for (int i = 0; i < 4; ++i) { xl[i] = xr[threadIdx.x + i * 256]; s += xl[i] * xl[i]; }
#pragma unroll
  for (int d = 1; d < 64; d <<= 1) s += __shfl_xor(s, d);
  __shared__ float red[4];
  int l = threadIdx.x & 63, w = threadIdx.x >> 6;
  if (l == 0) red[w] = s;
  __syncthreads();
  s = red[0] + red[1] + red[2] + red[3];
  float r = rsqrtf(s * (1.0f / DM) + 1e-5f);
  bf16_t* orow = out + (size_t)row * DM;
#pragma unroll
  for (int i = 0; i < 4; ++i) {
    int j = threadIdx.x + i * 256;
    float sc = ss[b * 2048 + j], sh = ss[b * 2048 + 1024 + j];
    orow[j] = (bf16_t)(xl[i] * r * wnorm[j] * (1.0f + sc) + sh);
  }
}

// ---------------- RoPE in-place on q and k -----------------------------------------
__global__ __launch_bounds__(256) void rope_apply_k(bf16_t* __restrict__ q,
    bf16_t* __restrict__ k, const float* __restrict__ cs) {
  int idx = blockIdx.x * 256 + threadIdx.x;     // 0..2^22-1
  int which = idx >> 21;
  int r = idx & ((1 << 21) - 1);
  int i = r & 31;
  int h = (r >> 5) & 15;
  int s = (r >> 9) & 2047;
  int b = (r >> 20) & 1;
  bf16_t* p = which ? k : q;
  size_t base = (((size_t)(b * S_LEN + s)) * NH + h) * HD;
  float x1 = (float)p[base + i], x2 = (float)p[base + i + 32];
  float c = cs[s * 64 + i], sn = cs[S_LEN * 64 + s * 64 + i];
  p[base + i]      = (bf16_t)(x1 * c - x2 * sn);
  p[base + i + 32] = (bf16_t)(x2 * c + x1 * sn);
}

// ---------------- fp32 [K][N] -> bf16 [N][K] transpose-convert ---------------------
__global__ __launch_bounds__(256) void conv_t_k(const float* __restrict__ in,
    bf16_t* __restrict__ out, int K, int N) {
  __shared__ float t[32][33];
  int n0 = blockIdx.x * 32, k0 = blockIdx.y * 32;
  int tx = threadIdx.x & 31, ty = threadIdx.x >> 5;
#pragma unroll
  for (int i = 0; i < 32; i += 8)
    t[ty + i][tx] = in[(size_t)(k0 + ty + i) * N + n0 + tx];
  __syncthreads();
#pragma unroll
  for (int i = 0; i < 32; i += 8)
    out[(size_t)(n0 + ty + i) * K + k0 + tx] = (bf16_t)t[tx][ty + i];
}

// ---------------- bf16 MFMA GEMM: C = A[M][K] @ BT[N][K]^T, fused epilogues --------
// EPI: 0 = +bias -> bf16 out          (QKV)
//      1 = +bias +resid -> f32 out    (WO + residual)
//      2 = exact GELU -> bf16 out     (gate)
//      3 = out *= acc (in-place mult) (up: h = gelu(g) * up)
//      4 = +resid -> f32 out          (down + residual -> d_out)
template<int EPI>
__global__ __launch_bounds__(256) void gemm_bt(
    const bf16_t* __restrict__ A, const bf16_t* __restrict__ BT,
    int M, int N, int K,
    const float* __restrict__ bias, const float* __restrict__ resid,
    bf16_t* outb, float* outf) {
  const int col0 = blockIdx.x * 128, row0 = blockIdx.y * 128;
  const int tid = threadIdx.x, l = tid & 63, w = tid >> 6;
  const int wr = (w >> 1) * 64, wc = (w & 1) * 64;
  const int lo = l & 15, hi = l >> 4;
  __shared__ __align__(16) bf16_t lA[128][72];   // +8 pad: fragment reads 2-way (free)
  __shared__ __align__(16) bf16_t lB[128][72];
  f32x4 zero = {0.f, 0.f, 0.f, 0.f};
  f32x4 acc[4][4];
#pragma unroll
  for (int m = 0; m < 4; ++m)
#pragma unroll
    for (int n = 0; n < 4; ++n) acc[m][n] = zero;

  for (int k0 = 0; k0 < K; k0 += 64) {
    __syncthreads();
#pragma unroll
    for (int i = 0; i < 4; ++i) {
      int c = tid + i * 256;
      int r = c >> 3, kc = (c & 7) * 8;
      *(uint4*)&lA[r][kc] = *(const uint4*)&A[(size_t)(row0 + r) * K + k0 + kc];
      *(uint4*)&lB[r][kc] = *(const uint4*)&BT[(size_t)(col0 + r) * K + k0 + kc];
    }
    __syncthreads();
#pragma unroll
    for (int kk = 0; kk < 64; kk += 32) {
      bf16x8 af[4], bfr[4];
#pragma unroll
      for (int m = 0; m < 4; ++m) af[m] = *(const bf16x8*)&lA[wr + m * 16 + lo][kk + hi * 8];
#pragma unroll
      for (int n = 0; n < 4; ++n) bfr[n] = *(const bf16x8*)&lB[wc + n * 16 + lo][kk + hi * 8];
#pragma unroll
      for (int m = 0; m < 4; ++m)
#pragma unroll
        for (int n = 0; n < 4; ++n)
          acc[m][n] = __builtin_amdgcn_mfma_f32_16x16x32_bf16(af[m], bfr[n], acc[m][n], 0, 0, 0);
    }
  }
#pragma unroll
  for (int m = 0; m < 4; ++m) {
#pragma unroll
    for (int n = 0; n < 4; ++n) {
#pragma unroll
      for (int j = 0; j < 4; ++j) {
        int r = row0 + wr + m * 16 + hi * 4 + j;      // C/D: row=(l>>4)*4+reg
        int cl = col0 + wc + n * 16 + lo;             //      col=l&15   (m89-verified)
        size_t idx = (size_t)r * N + cl;
        float vv = acc[m][n][j];
        if (EPI == 0)      { vv += bias[cl]; outb[idx] = (bf16_t)vv; }
        else if (EPI == 1) { vv += bias[cl] + resid[idx]; outf[idx] = vv; }
        else if (EPI == 2) { vv = 0.5f * vv * (1.0f + erff(vv * 0.70710678118f)); outb[idx] = (bf16_t)vv; }
        else if (EPI == 3) { float gv = (float)outb[idx]; outb[idx] = (bf16_t)(gv * vv); }
        else               { vv += resid[idx]; outf[idx] = vv; }
      }
    }
  }
}

// ---------------- flash attention: 4 waves x 16 q-rows, KV tile = 32 ---------------
__global__ __launch_bounds__(256) void attn_k(const bf16_t* __restrict__ q,
    const bf16_t* __restrict__ k, const bf16_t* __restrict__ v,
    bf16_t* __restrict__ o) {
  const int bh = blockIdx.y;            // b*16+h
  const int b = bh >> 4, h = bh & 15;
  const int q0 = blockIdx.x * 64;
  const int tid = threadIdx.x, l = tid & 63, w = tid >> 6;
  const int lo = l & 15, hi = l >> 4;
  __shared__ __align__(16) bf16_t lq[64][72];
  __shared__ __align__(16) bf16_t lk[32][72];
  __shared__ __align__(16) bf16_t lvt[64][40];   // V^T: [d][kv]
  __shared__ __align__(16) bf16_t lp[4][16][40]; // per-wave P relayout buffer

#pragma unroll
  for (int i = 0; i < 2; ++i) {
    int c = tid + i * 256;
    int r = c >> 3, dc = (c & 7) * 8;
    *(uint4*)&lq[r][dc] = *(const uint4*)&q[(((size_t)(b * S_LEN) + q0 + r) * NH + h) * HD + dc];
  }
  f32x4 zero = {0.f, 0.f, 0.f, 0.f};
  f32x4 oa[4];
#pragma unroll
  for (int n = 0; n < 4; ++n) oa[n] = zero;
  float mrow[4] = {-1e30f, -1e30f, -1e30f, -1e30f};
  float lrow[4] = {0.f, 0.f, 0.f, 0.f};

  for (int t0 = 0; t0 < S_LEN; t0 += 32) {
    __syncthreads();
    {
      int r = tid >> 3, dc = (tid & 7) * 8;
      *(uint4*)&lk[r][dc] = *(const uint4*)&k[(((size_t)(b * S_LEN) + t0 + r) * NH + h) * HD + dc];
      uint4 vv = *(const uint4*)&v[(((size_t)(b * S_LEN) + t0 + r) * NH + h) * HD + dc];
      __align__(16) bf16_t tmp[8];
      *(uint4*)tmp = vv;
#pragma unroll
      for (int j = 0; j < 8; ++j) lvt[dc + j][r] = tmp[j];
    }
    __syncthreads();
    // S = Q(16x64) @ K^T(64x32), per wave
    f32x4 s0 = zero, s1 = zero;
#pragma unroll
    for (int kk = 0; kk < 64; kk += 32) {
      bf16x8 aq = *(const bf16x8*)&lq[w * 16 + lo][kk + hi * 8];
      s0 = __builtin_amdgcn_mfma_f32_16x16x32_bf16(aq, *(const bf16x8*)&lk[lo][kk + hi * 8], s0, 0, 0, 0);
      s1 = __builtin_amdgcn_mfma_f32_16x16x32_bf16(aq, *(const bf16x8*)&lk[16 + lo][kk + hi * 8], s1, 0, 0, 0);
    }
    // online softmax (row = hi*4+j, lanes sharing a row differ in low 4 bits)
#pragma unroll
    for (int j = 0; j < 4; ++j) {
      float a = s0[j] * 0.125f, bb = s1[j] * 0.125f;
      float mx = fmaxf(a, bb);
      mx = fmaxf(mx, __shfl_xor(mx, 1));
      mx = fmaxf(mx, __shfl_xor(mx, 2));
      mx = fmaxf(mx, __shfl_xor(mx, 4));
      mx = fmaxf(mx, __shfl_xor(mx, 8));
      float mn = fmaxf(mrow[j], mx);
      float corr = __expf(mrow[j] - mn);
      mrow[j] = mn;
      float p0 = __expf(a - mn), p1 = __expf(bb - mn);
      lrow[j] = lrow[j] * corr + p0 + p1;
#pragma unroll
      for (int n = 0; n < 4; ++n) oa[n][j] *= corr;
      lp[w][hi * 4 + j][lo] = (bf16_t)p0;
      lp[w][hi * 4 + j][16 + lo] = (bf16_t)p1;
    }
    // O += P(16x32) @ V(32x64)
    bf16x8 ap = *(const bf16x8*)&lp[w][lo][hi * 8];
#pragma unroll
    for (int n = 0; n < 4; ++n) {
      bf16x8 bv = *(const bf16x8*)&lvt[n * 16 + lo][hi * 8];
      oa[n] = __builtin_amdgcn_mfma_f32_16x16x32_bf16(ap, bv, oa[n], 0, 0, 0);
    }
  }
#pragma unroll
  for (int j = 0; j < 4; ++j) {
    float ls = lrow[j];
    ls += __shfl_xor(ls, 1); ls += __shfl_xor(ls, 2);
    ls += __shfl_xor(ls, 4); ls += __shfl_xor(ls, 8);
    float inv = 1.0f / ls;
    int row = q0 + w * 16 + hi * 4 + j;
#pragma unroll
    for (int n = 0; n < 4; ++n)
      o[(((size_t)(b * S_LEN) + row) * NH + h) * HD + n * 16 + lo] = (bf16_t)(oa[n][j] * inv);
  }
}

// ---------------------------------------------------------------------------------
extern "C" void kernel_launch(void* const* d_in, const int* in_sizes, int n_in,
                              void* d_out, int out_size, void* d_ws, size_t ws_size,
                              hipStream_t stream) {
  const float* x    = (const float*)d_in[0];
  const float* te   = (const float*)d_in[1];
  const float* wn1  = (const float*)d_in[2];
  const float* t1w1 = (const float*)d_in[3];
  const float* t1b1 = (const float*)d_in[4];
  const float* t1w2 = (const float*)d_in[5];
  const float* t1b2 = (const float*)d_in[6];
  const float* wn2  = (const float*)d_in[7];
  const float* t2w1 = (const float*)d_in[8];
  const float* t2b1 = (const float*)d_in[9];
  const float* t2w2 = (const float*)d_in[10];
  const float* t2b2 = (const float*)d_in[11];
  const float* wq   = (const float*)d_in[12];
  const float* bq   = (const float*)d_in[13];
  const float* wk   = (const float*)d_in[14];
  const float* bk   = (const float*)d_in[15];
  const float* wv   = (const float*)d_in[16];
  const float* bv   = (const float*)d_in[17];
  const float* wo   = (const float*)d_in[18];
  const float* bo   = (const float*)d_in[19];
  const float* wg   = (const float*)d_in[20];
  const float* wu   = (const float*)d_in[21];
  const float* wd   = (const float*)d_in[22];
  float* out = (float*)d_out;

  char* ws = (char*)d_ws;
  const size_t MB = 1ull << 20;
  bf16_t* wqT  = (bf16_t*)(ws + 0 * MB);
  bf16_t* wkT  = (bf16_t*)(ws + 2 * MB);
  bf16_t* wvT  = (bf16_t*)(ws + 4 * MB);
  bf16_t* woT  = (bf16_t*)(ws + 6 * MB);
  bf16_t* wgT  = (bf16_t*)(ws + 8 * MB);
  bf16_t* wuT  = (bf16_t*)(ws + 16 * MB);
  bf16_t* wdT  = (bf16_t*)(ws + 24 * MB);
  bf16_t* nx   = (bf16_t*)(ws + 32 * MB);
  bf16_t* qb   = (bf16_t*)(ws + 40 * MB);
  bf16_t* kb   = (bf16_t*)(ws + 48 * MB);
  bf16_t* vb   = (bf16_t*)(ws + 56 * MB);
  bf16_t* gb   = (bf16_t*)(ws + 40 * MB);   // aliases q/k/v/attn (dead by FFN time)
  bf16_t* attnb= (bf16_t*)(ws + 64 * MB);
  float*  x2   = (float*)(ws + 72 * MB);
  float*  cs   = (float*)(ws + 88 * MB);
  float*  ss1  = (float*)(ws + 89 * MB);
  float*  ss2  = (float*)(ws + 89 * MB + 65536);
  float*  htmp = (float*)(ws + 89 * MB + 131072);

  // RoPE table + adaLN scale/shift (depend only on te)
  rope_table_k<<<256, 256, 0, stream>>>(cs);
  time_mlp1_k<<<8, 256, 0, stream>>>(te, t1w1, t1b1, htmp);
  time_mlp2_k<<<16, 256, 0, stream>>>(htmp, t1w2, t1b2, ss1);
  time_mlp1_k<<<8, 256, 0, stream>>>(te, t2w1, t2b1, htmp);
  time_mlp2_k<<<16, 256, 0, stream>>>(htmp, t2w2, t2b2, ss2);

  // weight convert + transpose to bf16 [N][K]
  conv_t_k<<<dim3(32, 32),  256, 0, stream>>>(wq, wqT, 1024, 1024);
  conv_t_k<<<dim3(32, 32),  256, 0, stream>>>(wk, wkT, 1024, 1024);
  conv_t_k<<<dim3(32, 32),  256, 0, stream>>>(wv, wvT, 1024, 1024);
  conv_t_k<<<dim3(32, 32),  256, 0, stream>>>(wo, woT, 1024, 1024);
  conv_t_k<<<dim3(128, 32), 256, 0, stream>>>(wg, wgT, 1024, 4096);
  conv_t_k<<<dim3(128, 32), 256, 0, stream>>>(wu, wuT, 1024, 4096);
  conv_t_k<<<dim3(32, 128), 256, 0, stream>>>(wd, wdT, 4096, 1024);

  // norm1 -> nx (bf16)
  ada_rms_k<<<MROWS, 256, 0, stream>>>(x, wn1, ss1, nx);

  // QKV projections
  dim3 g1(8, 32);
  gemm_bt<0><<<g1, 256, 0, stream>>>(nx, wqT, MROWS, DM, DM, bq, nullptr, qb, nullptr);
  gemm_bt<0><<<g1, 256, 0, stream>>>(nx, wkT, MROWS, DM, DM, bk, nullptr, kb, nullptr);
  gemm_bt<0><<<g1, 256, 0, stream>>>(nx, wvT, MROWS, DM, DM, bv, nullptr, vb, nullptr);

  // RoPE on q,k
  rope_apply_k<<<16384, 256, 0, stream>>>(qb, kb, cs);

  // attention
  attn_k<<<dim3(S_LEN / 64, NBATCH * NH), 256, 0, stream>>>(qb, kb, vb, attnb);

  // WO + bias + residual -> x2 (fp32)
  gemm_bt<1><<<g1, 256, 0, stream>>>(attnb, woT, MROWS, DM, DM, bo, x, nullptr, x2);

  // norm2 -> nx (bf16, reuse buffer)
  ada_rms_k<<<MROWS, 256, 0, stream>>>(x2, wn2, ss2, nx);

  // FFN: g = gelu(nx@wg); g *= nx@wu; out = g@wd + x2
  dim3 g2(32, 32);
  gemm_bt<2><<<g2, 256, 0, stream>>>(nx, wgT, MROWS, DFF, DM, nullptr, nullptr, gb, nullptr);
  gemm_bt<3><<<g2, 256, 0, stream>>>(nx, wuT, MROWS, DFF, DM, nullptr, nullptr, gb, nullptr);
  gemm_bt<4><<<g1, 256, 0, stream>>>(gb, wdT, MROWS, DM, DFF, nullptr, x2, nullptr, out);
}

// Round 2
// 456.754 us; speedup vs baseline: 1.5309x; 1.5309x over previous
//
#include <hip/hip_runtime.h>
#include <hip/hip_bf16.h>

typedef __bf16 bf16_t;
typedef __bf16 bf16x8 __attribute__((ext_vector_type(8)));
typedef float f32x4 __attribute__((ext_vector_type(4)));

static constexpr int S_LEN = 2048;
static constexpr int NBATCH = 2;
static constexpr int DM = 1024;
static constexpr int NH = 16;
static constexpr int HD = 64;
static constexpr int DFF = 4096;
static constexpr int MROWS = NBATCH * S_LEN;   // 4096
static constexpr int QKVN = 3072;              // merged q|k|v columns

// ---------------- RoPE cos/sin table: cs[0..S*64) = cos, cs[S*64..) = sin ---------
__global__ __launch_bounds__(256) void rope_table_k(float* __restrict__ cs) {
  int idx = blockIdx.x * 256 + threadIdx.x;     // 0 .. 2048*32-1
  int i = idx & 31, s = idx >> 5;
  float inv = powf(10000.0f, -(float)i / 32.0f);  // theta^{-2i/64}
  float ang = (float)s * inv;
  float c = cosf(ang), sn = sinf(ang);
  cs[s * 64 + i] = c;  cs[s * 64 + i + 32] = c;
  cs[S_LEN * 64 + s * 64 + i] = sn;  cs[S_LEN * 64 + s * 64 + i + 32] = sn;
}

// ---------------- GEMV: out[b][j] = act(vin[b] . W[:,j] + bias[j]) ------------------
// W is [1024][N] row-major (j fastest). 32 j per block, 8-way i-split.
__global__ __launch_bounds__(256) void gemv_k(const float* __restrict__ vin,
    const float* __restrict__ W, const float* __restrict__ bias,
    float* __restrict__ out, int N, int dosilu) {
  int b = blockIdx.y;
  int tj = threadIdx.x & 31, ti = threadIdx.x >> 5;
  int j = blockIdx.x * 32 + tj;
  const float* v = vin + b * DM;
  float acc = 0.f;
  int i0 = ti * 128;
#pragma unroll 8
  for (int i = i0; i < i0 + 128; ++i) acc += v[i] * W[(size_t)i * N + j];
  __shared__ float red[8][32];
  red[ti][tj] = acc;
  __syncthreads();
  if (threadIdx.x < 32) {
    float a = 0.f;
#pragma unroll
    for (int t = 0; t < 8; ++t) a += red[t][threadIdx.x];
    a += bias[j - tj + threadIdx.x];
    if (dosilu) a = a / (1.0f + expf(-a));
    out[(size_t)b * N + blockIdx.x * 32 + threadIdx.x] = a;
  }
}

// ---------------- bias concat for merged QKV ---------------------------------------
__global__ __launch_bounds__(256) void bcat_k(const float* __restrict__ bq,
    const float* __restrict__ bk, const float* __restrict__ bv, float* __restrict__ o) {
  int i = blockIdx.x * 256 + threadIdx.x;   // 0..3071
  o[i] = i < 1024 ? bq[i] : (i < 2048 ? bk[i - 1024] : bv[i - 2048]);
}

// ---------------- ada-RMSNorm: out = x*rsqrt(mean x^2+eps)*w*(1+scale)+shift -------
template<typename T>
__global__ __launch_bounds__(256) void ada_rms_k(const T* __restrict__ x,
    const float* __restrict__ wnorm, const float* __restrict__ ss,
    bf16_t* __restrict__ out) {
  int row = blockIdx.x;                // 0..4095  (b = row/2048)
  int b = row >> 11;
  const T* xr = x + (size_t)row * DM;
  float xl[4]; float s = 0.f;
#pragma unroll
  for (int i = 0; i < 4; ++i) { xl[i] = (float)xr[threadIdx.x + i * 256]; s += xl[i] * xl[i]; }
#pragma unroll
  for (int d = 1; d < 64; d <<= 1) s += __shfl_xor(s, d);
  __shared__ float red[4];
  int w = threadIdx.x >> 6;
  if ((threadIdx.x & 63) == 0) red[w] = s;
  __syncthreads();
  s = red[0] + red[1] + red[2] + red[3];
  float r = rsqrtf(s * (1.0f / DM) + 1e-5f);
  bf16_t* orow = out + (size_t)row * DM;
#pragma unroll
  for (int i = 0; i < 4; ++i) {
    int j = threadIdx.x + i * 256;
    float sc = ss[b * 2048 + j], sh = ss[b * 2048 + 1024 + j];
    orow[j] = (bf16_t)(xl[i] * r * wnorm[j] * (1.0f + sc) + sh);
  }
}

// ---------------- RoPE in-place on merged qkv (q scaled by 1/8) --------------------
__global__ __launch_bounds__(256) void rope_apply_k(bf16_t* __restrict__ qkv,
    const float* __restrict__ cs) {
  int idx = blockIdx.x * 256 + threadIdx.x;     // 0..2^22-1
  int which = idx >> 21;                        // 0=q, 1=k
  int r = idx & ((1 << 21) - 1);
  int i = r & 31;
  int h = (r >> 5) & 15;
  int s = (r >> 9) & 2047;
  int b = (r >> 20) & 1;
  size_t base = ((size_t)(b * S_LEN + s)) * QKVN + which * 1024 + h * HD;
  float x1 = (float)qkv[base + i], x2 = (float)qkv[base + i + 32];
  float c = cs[s * 64 + i], sn = cs[S_LEN * 64 + s * 64 + i];
  float scale = which ? 1.0f : 0.125f;          // fold 1/sqrt(64) into q
  qkv[base + i]      = (bf16_t)((x1 * c - x2 * sn) * scale);
  qkv[base + i + 32] = (bf16_t)((x2 * c + x1 * sn) * scale);
}

// ---------------- V part of qkv -> V^T  [bh][d][s] ---------------------------------
__global__ __launch_bounds__(256) void vtrans_k(const bf16_t* __restrict__ qkv,
    bf16_t* __restrict__ vt) {
  int sb = blockIdx.x;       // s-block (64 rows)
  int bh = blockIdx.y;       // b*16+h
  int b = bh >> 4, h = bh & 15;
  __shared__ bf16_t t[64][72];
  int tid = threadIdx.x;
#pragma unroll
  for (int it = 0; it < 2; ++it) {
    int c = tid + it * 256;
    int r = c >> 3, dc = (c & 7) * 8;
    int key = ((r >> 3) & 7) * 8;
    *(uint4*)&t[r][dc ^ key] =
      *(const uint4*)&qkv[((size_t)(b * S_LEN) + sb * 64 + r) * QKVN + 2048 + h * HD + dc];
  }
  __syncthreads();
#pragma unroll
  for (int it = 0; it < 2; ++it) {
    int c = tid + it * 256;
    int d = c >> 3, sc = (c & 7) * 8;
    __align__(16) bf16_t tmp[8];
#pragma unroll
    for (int jj = 0; jj < 8; ++jj) {
      int row = sc + jj;
      int key = ((row >> 3) & 7) * 8;
      tmp[jj] = t[row][d ^ key];
    }
    *(uint4*)&vt[((size_t)bh * 64 + d) * S_LEN + sb * 64 + sc] = *(uint4*)tmp;
  }
}

// ---------------- fp32 [K][N] -> bf16 [N][K] transpose-convert ---------------------
__global__ __launch_bounds__(256) void conv_t_k(const float* __restrict__ in,
    bf16_t* __restrict__ out, int K, int N) {
  __shared__ float t[32][33];
  int n0 = blockIdx.x * 32, k0 = blockIdx.y * 32;
  int tx = threadIdx.x & 31, ty = threadIdx.x >> 5;
#pragma unroll
  for (int i = 0; i < 32; i += 8)
    t[ty + i][tx] = in[(size_t)(k0 + ty + i) * N + n0 + tx];
  __syncthreads();
#pragma unroll
  for (int i = 0; i < 32; i += 8)
    out[(size_t)(n0 + ty + i) * K + k0 + tx] = (bf16_t)t[tx][ty + i];
}

// ---------------- bf16 MFMA GEMM: C = A[M][K] @ BT[N][K]^T, fused epilogues --------
// EPI: 0 = +bias -> bf16 out              (QKV merged)
//      1 = +bias +residf(f32) -> bf16 out (WO + residual -> x2)
//      2 = exact GELU -> bf16 out         (gate)
//      3 = out *= acc (in-place mult)     (up: h = gelu(g) * up)
//      4 = +residb(bf16) -> f32 out       (down + residual -> d_out)
template<int EPI>
__global__ __launch_bounds__(256) void gemm_bt(
    const bf16_t* __restrict__ A, const bf16_t* __restrict__ BT,
    int M, int N, int K,
    const float* __restrict__ bias, const float* __restrict__ residf,
    const bf16_t* __restrict__ residb, bf16_t* outb, float* outf) {
  const int col0 = blockIdx.x * 128, row0 = blockIdx.y * 128;
  const int tid = threadIdx.x, l = tid & 63, w = tid >> 6;
  const int wr = (w >> 1) * 64, wc = (w & 1) * 64;
  const int lo = l & 15, hi = l >> 4;
  __shared__ __align__(16) bf16_t lA[128][72];   // +8 pad: fragment reads 2-way (free)
  __shared__ __align__(16) bf16_t lB[128][72];
  f32x4 zero = {0.f, 0.f, 0.f, 0.f};
  f32x4 acc[4][4];
#pragma unroll
  for (int m = 0; m < 4; ++m)
#pragma unroll
    for (int n = 0; n < 4; ++n) acc[m][n] = zero;

  for (int k0 = 0; k0 < K; k0 += 64) {
    __syncthreads();
#pragma unroll
    for (int i = 0; i < 4; ++i) {
      int c = tid + i * 256;
      int r = c >> 3, kc = (c & 7) * 8;
      *(uint4*)&lA[r][kc] = *(const uint4*)&A[(size_t)(row0 + r) * K + k0 + kc];
      *(uint4*)&lB[r][kc] = *(const uint4*)&BT[(size_t)(col0 + r) * K + k0 + kc];
    }
    __syncthreads();
#pragma unroll
    for (int kk = 0; kk < 64; kk += 32) {
      bf16x8 af[4], bfr[4];
#pragma unroll
      for (int m = 0; m < 4; ++m) af[m] = *(const bf16x8*)&lA[wr + m * 16 + lo][kk + hi * 8];
#pragma unroll
      for (int n = 0; n < 4; ++n) bfr[n] = *(const bf16x8*)&lB[wc + n * 16 + lo][kk + hi * 8];
#pragma unroll
      for (int m = 0; m < 4; ++m)
#pragma unroll
        for (int n = 0; n < 4; ++n)
          acc[m][n] = __builtin_amdgcn_mfma_f32_16x16x32_bf16(af[m], bfr[n], acc[m][n], 0, 0, 0);
    }
  }
#pragma unroll
  for (int m = 0; m < 4; ++m) {
#pragma unroll
    for (int n = 0; n < 4; ++n) {
#pragma unroll
      for (int j = 0; j < 4; ++j) {
        int r = row0 + wr + m * 16 + hi * 4 + j;      // C/D: row=(l>>4)*4+reg
        int cl = col0 + wc + n * 16 + lo;             //      col=l&15   (m89-verified)
        size_t idx = (size_t)r * N + cl;
        float vv = acc[m][n][j];
        if (EPI == 0)      { vv += bias[cl]; outb[idx] = (bf16_t)vv; }
        else if (EPI == 1) { vv += bias[cl] + residf[idx]; outb[idx] = (bf16_t)vv; }
        else if (EPI == 2) { vv = 0.5f * vv * (1.0f + erff(vv * 0.70710678118f)); outb[idx] = (bf16_t)vv; }
        else if (EPI == 3) { float gv = (float)outb[idx]; outb[idx] = (bf16_t)(gv * vv); }
        else               { vv += (float)residb[idx]; outf[idx] = vv; }
      }
    }
  }
}

// ---------------- flash attention: 4 waves x 32 q-rows, KV tile = 64 ---------------
// qk: merged qkv buffer (q at col 0, k at col 1024, stride 3072), q pre-scaled 1/8.
// vt: [bh][d][s].  o: [row][h*64+d] (stride 1024).
__global__ __launch_bounds__(256) void attn_k(const bf16_t* __restrict__ qk,
    const bf16_t* __restrict__ vt, bf16_t* __restrict__ o) {
  // XCD swizzle: 512 blocks, 8 XCDs -> 64 consecutive origs (4 bh groups) per XCD
  int g = blockIdx.x;
  int orig = (g & 7) * 64 + (g >> 3);
  int qblk = orig & 15;
  int bh = orig >> 4;
  int b = bh >> 4, h = bh & 15;
  const int q0 = qblk * 128;
  const int tid = threadIdx.x, l = tid & 63, w = tid >> 6;
  const int lo = l & 15, hi = l >> 4;

  __shared__ __align__(16) bf16_t lq[128][72];
  __shared__ __align__(16) bf16_t lk[64][72];
  __shared__ __align__(16) bf16_t lvt[64][72];   // [d][kv]
  __shared__ __align__(16) bf16_t lp[4][32][72]; // per-wave P

  // stage Q (128 rows x 64)
#pragma unroll
  for (int it = 0; it < 4; ++it) {
    int c = tid + it * 256;
    int r = c >> 3, dc = (c & 7) * 8;
    *(uint4*)&lq[r][dc] =
      *(const uint4*)&qk[((size_t)(b * S_LEN) + q0 + r) * QKVN + h * HD + dc];
  }

  f32x4 zero = {0.f, 0.f, 0.f, 0.f};
  f32x4 oa[2][4];
#pragma unroll
  for (int m = 0; m < 2; ++m)
#pragma unroll
    for (int n = 0; n < 4; ++n) oa[m][n] = zero;
  float mrow[2][4], lrow[2][4];
#pragma unroll
  for (int m = 0; m < 2; ++m)
#pragma unroll
    for (int j = 0; j < 4; ++j) { mrow[m][j] = -1e30f; lrow[m][j] = 0.f; }

  const size_t kbase = (size_t)(b * S_LEN) * QKVN + 1024 + h * HD;
  const size_t vbase = (size_t)bh * 64 * S_LEN;

  for (int t0 = 0; t0 < S_LEN; t0 += 64) {
    __syncthreads();
#pragma unroll
    for (int it = 0; it < 2; ++it) {
      int c = tid + it * 256;
      int r = c >> 3, dc = (c & 7) * 8;
      *(uint4*)&lk[r][dc]  = *(const uint4*)&qk[kbase + (size_t)(t0 + r) * QKVN + dc];
      *(uint4*)&lvt[r][dc] = *(const uint4*)&vt[vbase + (size_t)r * S_LEN + t0 + dc];
    }
    __syncthreads();

    // S = Q(32x64) @ K^T  -> s[m][n], rows w*32+m*16+(hi*4+j), cols n*16+lo
    f32x4 s[2][4];
#pragma unroll
    for (int m = 0; m < 2; ++m)
#pragma unroll
      for (int n = 0; n < 4; ++n) s[m][n] = zero;
#pragma unroll
    for (int kk = 0; kk < 64; kk += 32) {
      bf16x8 aq[2], bk[4];
#pragma unroll
      for (int m = 0; m < 2; ++m) aq[m] = *(const bf16x8*)&lq[w * 32 + m * 16 + lo][kk + hi * 8];
#pragma unroll
      for (int n = 0; n < 4; ++n) bk[n] = *(const bf16x8*)&lk[n * 16 + lo][kk + hi * 8];
#pragma unroll
      for (int m = 0; m < 2; ++m)
#pragma unroll
        for (int n = 0; n < 4; ++n)
          s[m][n] = __builtin_amdgcn_mfma_f32_16x16x32_bf16(aq[m], bk[n], s[m][n], 0, 0, 0);
    }

    // online softmax; write P to per-wave LDS
#pragma unroll
    for (int m = 0; m < 2; ++m) {
#pragma unroll
      for (int j = 0; j < 4; ++j) {
        float mx = fmaxf(fmaxf(s[m][0][j], s[m][1][j]), fmaxf(s[m][2][j], s[m][3][j]));
        mx = fmaxf(mx, __shfl_xor(mx, 1));
        mx = fmaxf(mx, __shfl_xor(mx, 2));
        mx = fmaxf(mx, __shfl_xor(mx, 4));
        mx = fmaxf(mx, __shfl_xor(mx, 8));
        float mn = fmaxf(mrow[m][j], mx);
        float corr = __expf(mrow[m][j] - mn);
        mrow[m][j] = mn;
        float psum = 0.f;
#pragma unroll
        for (int n = 0; n < 4; ++n) {
          float p = __expf(s[m][n][j] - mn);
          psum += p;
          lp[w][m * 16 + hi * 4 + j][n * 16 + lo] = (bf16_t)p;
        }
        lrow[m][j] = lrow[m][j] * corr + psum;
#pragma unroll
        for (int n = 0; n < 4; ++n) oa[m][n][j] *= corr;
      }
    }

    // O += P(32x64) @ V(64x64)   (B operand = lvt[d][kv])
#pragma unroll
    for (int kk = 0; kk < 64; kk += 32) {
      bf16x8 ap[2], bv[4];
#pragma unroll
      for (int m = 0; m < 2; ++m) ap[m] = *(const bf16x8*)&lp[w][m * 16 + lo][kk + hi * 8];
#pragma unroll
      for (int n = 0; n < 4; ++n) bv[n] = *(const bf16x8*)&lvt[n * 16 + lo][kk + hi * 8];
#pragma unroll
      for (int m = 0; m < 2; ++m)
#pragma unroll
        for (int n = 0; n < 4; ++n)
          oa[m][n] = __builtin_amdgcn_mfma_f32_16x16x32_bf16(ap[m], bv[n], oa[m][n], 0, 0, 0);
    }
  }

#pragma unroll
  for (int m = 0; m < 2; ++m) {
#pragma unroll
    for (int j = 0; j < 4; ++j) {
      float ls = lrow[m][j];
      ls += __shfl_xor(ls, 1); ls += __shfl_xor(ls, 2);
      ls += __shfl_xor(ls, 4); ls += __shfl_xor(ls, 8);
      float inv = 1.0f / ls;
      int row = q0 + w * 32 + m * 16 + hi * 4 + j;
#pragma unroll
      for (int n = 0; n < 4; ++n)
        o[((size_t)(b * S_LEN) + row) * DM + h * HD + n * 16 + lo] = (bf16_t)(oa[m][n][j] * inv);
    }
  }
}

// ---------------------------------------------------------------------------------
extern "C" void kernel_launch(void* const* d_in, const int* in_sizes, int n_in,
                              void* d_out, int out_size, void* d_ws, size_t ws_size,
                              hipStream_t stream) {
  const float* x    = (const float*)d_in[0];
  const float* te   = (const float*)d_in[1];
  const float* wn1  = (const float*)d_in[2];
  const float* t1w1 = (const float*)d_in[3];
  const float* t1b1 = (const float*)d_in[4];
  const float* t1w2 = (const float*)d_in[5];
  const float* t1b2 = (const float*)d_in[6];
  const float* wn2  = (const float*)d_in[7];
  const float* t2w1 = (const float*)d_in[8];
  const float* t2b1 = (const float*)d_in[9];
  const float* t2w2 = (const float*)d_in[10];
  const float* t2b2 = (const float*)d_in[11];
  const float* wq   = (const float*)d_in[12];
  const float* bq   = (const float*)d_in[13];
  const float* wk   = (const float*)d_in[14];
  const float* bk   = (const float*)d_in[15];
  const float* wv   = (const float*)d_in[16];
  const float* bv   = (const float*)d_in[17];
  const float* wo   = (const float*)d_in[18];
  const float* bo   = (const float*)d_in[19];
  const float* wg   = (const float*)d_in[20];
  const float* wu   = (const float*)d_in[21];
  const float* wd   = (const float*)d_in[22];
  float* out = (float*)d_out;

  char* ws = (char*)d_ws;
  const size_t MB = 1ull << 20;
  bf16_t* woT   = (bf16_t*)(ws + 0 * MB);    // 2 MB
  bf16_t* wgT   = (bf16_t*)(ws + 2 * MB);    // 8 MB
  bf16_t* wuT   = (bf16_t*)(ws + 10 * MB);   // 8 MB
  bf16_t* wdT   = (bf16_t*)(ws + 18 * MB);   // 8 MB
  bf16_t* nx    = (bf16_t*)(ws + 26 * MB);   // 8 MB
  bf16_t* wqkvT = (bf16_t*)(ws + 34 * MB);   // 6 MB
  bf16_t* qkvb  = (bf16_t*)(ws + 40 * MB);   // 24 MB
  bf16_t* vt    = (bf16_t*)(ws + 64 * MB);   // 8 MB
  bf16_t* gb    = (bf16_t*)(ws + 40 * MB);   // 32 MB, aliases qkvb+vt (dead by FFN)
  bf16_t* attnb = (bf16_t*)(ws + 72 * MB);   // 8 MB
  bf16_t* x2b   = (bf16_t*)(ws + 80 * MB);   // 8 MB
  float*  cs    = (float*)(ws + 88 * MB);    // 1 MB
  float*  ss1   = (float*)(ws + 89 * MB);
  float*  ss2   = (float*)(ws + 89 * MB + 16384);
  float*  htmp  = (float*)(ws + 89 * MB + 32768);
  float*  bcat  = (float*)(ws + 89 * MB + 40960);

  // RoPE table + adaLN scale/shift (depend only on te) + bias concat
  rope_table_k<<<256, 256, 0, stream>>>(cs);
  bcat_k<<<12, 256, 0, stream>>>(bq, bk, bv, bcat);
  gemv_k<<<dim3(32, 2), 256, 0, stream>>>(te, t1w1, t1b1, htmp, 1024, 1);
  gemv_k<<<dim3(64, 2), 256, 0, stream>>>(htmp, t1w2, t1b2, ss1, 2048, 0);
  gemv_k<<<dim3(32, 2), 256, 0, stream>>>(te, t2w1, t2b1, htmp, 1024, 1);
  gemv_k<<<dim3(64, 2), 256, 0, stream>>>(htmp, t2w2, t2b2, ss2, 2048, 0);

  // weight convert + transpose to bf16 [N][K]
  conv_t_k<<<dim3(32, 32),  256, 0, stream>>>(wq, wqkvT,               1024, 1024);
  conv_t_k<<<dim3(32, 32),  256, 0, stream>>>(wk, wqkvT + 1024 * 1024, 1024, 1024);
  conv_t_k<<<dim3(32, 32),  256, 0, stream>>>(wv, wqkvT + 2048 * 1024, 1024, 1024);
  conv_t_k<<<dim3(32, 32),  256, 0, stream>>>(wo, woT, 1024, 1024);
  conv_t_k<<<dim3(128, 32), 256, 0, stream>>>(wg, wgT, 1024, 4096);
  conv_t_k<<<dim3(128, 32), 256, 0, stream>>>(wu, wuT, 1024, 4096);
  conv_t_k<<<dim3(32, 128), 256, 0, stream>>>(wd, wdT, 4096, 1024);

  // norm1 -> nx (bf16)
  ada_rms_k<float><<<MROWS, 256, 0, stream>>>(x, wn1, ss1, nx);

  // merged QKV projection
  gemm_bt<0><<<dim3(24, 32), 256, 0, stream>>>(nx, wqkvT, MROWS, QKVN, DM,
                                               bcat, nullptr, nullptr, qkvb, nullptr);

  // RoPE on q,k (q scaled 1/8); V -> V^T
  rope_apply_k<<<16384, 256, 0, stream>>>(qkvb, cs);
  vtrans_k<<<dim3(32, 32), 256, 0, stream>>>(qkvb, vt);

  // attention
  attn_k<<<512, 256, 0, stream>>>(qkvb, vt, attnb);

  // WO + bias + residual -> x2 (bf16)
  gemm_bt<1><<<dim3(8, 32), 256, 0, stream>>>(attnb, woT, MROWS, DM, DM,
                                              bo, x, nullptr, x2b, nullptr);

  // norm2 -> nx
  ada_rms_k<bf16_t><<<MROWS, 256, 0, stream>>>(x2b, wn2, ss2, nx);

  // FFN: g = gelu(nx@wg); g *= nx@wu; out = g@wd + x2
  gemm_bt<2><<<dim3(32, 32), 256, 0, stream>>>(nx, wgT, MROWS, DFF, DM,
                                               nullptr, nullptr, nullptr, gb, nullptr);
  gemm_bt<3><<<dim3(32, 32), 256, 0, stream>>>(nx, wuT, MROWS, DFF, DM,
                                               nullptr, nullptr, nullptr, gb, nullptr);
  gemm_bt<4><<<dim3(8, 32), 256, 0, stream>>>(gb, wdT, MROWS, DM, DFF,
                                              nullptr, nullptr, x2b, nullptr, out);
}